// Round 6
// baseline (127.109 us; speedup 1.0000x reference)
//
#include <hip/hip_runtime.h>
#include <hip/hip_bf16.h>

#define B_ 8
#define S_ 2048
#define D_ 1024
#define H_ 64

typedef __attribute__((ext_vector_type(8))) short bf16x8;
typedef __attribute__((ext_vector_type(4))) float f32x4;
typedef __attribute__((ext_vector_type(4))) unsigned short u16x4;
typedef unsigned short u16;

// fold 1/sqrt(64) and log2(e) into Q so softmax can use exp2
#define QSCALE 0.18033688011112042f

static __device__ __forceinline__ u16 f2bf(float f) {
  union { float f; unsigned u; } v; v.f = f;
  unsigned r = v.u + 0x7FFFu + ((v.u >> 16) & 1u);
  return (u16)(r >> 16);
}

// Build Wt [192][1024] bf16: rows 0..63 = Wq cols, 64..127 = Wk, 128..191 = Wv.
__global__ __launch_bounds__(256) void wprep_kernel(const float* __restrict__ Wk,
                                                    const float* __restrict__ Wq,
                                                    const float* __restrict__ Wv,
                                                    u16* __restrict__ Wt) {
  const int c = blockIdx.x;  // 0..191
  const float* W = (c < 64) ? Wq : ((c < 128) ? Wk : Wv);
  const int cc = c & 63;
  for (int d = threadIdx.x; d < D_; d += blockDim.x)
    Wt[c * D_ + d] = f2bf(W[d * H_ + cc]);
}

// QKV projection, 16 rows/block, 8-way K-split.
// Block = 512 threads = 8 waves; wave w covers K [w*128,(w+1)*128) of the SAME
// 16 rows x 192 cols (acc[12]). 3-stage LDS tree-reduce; wave 0 epilogue.
// Grid = 1024 blocks; launch_bounds(512,4) -> 2 blocks/CU = 4 waves/SIMD.
__global__ __launch_bounds__(512, 4) void qkv_kernel(const float* __restrict__ x,
                                                     const u16* __restrict__ Wt,
                                                     u16* __restrict__ Qb,
                                                     u16* __restrict__ Kb,
                                                     u16* __restrict__ Vt) {
  __shared__ float red[4][64][52];  // 53 KB; stride 52 -> 16B-aligned b128

  const long row0 = (long)blockIdx.x * 16;
  const int w = threadIdx.x >> 6;      // 0..7
  const int lane = threadIdx.x & 63;
  const int r = lane & 15;
  const int g = lane >> 4;

  f32x4 acc[12];
#pragma unroll
  for (int nf = 0; nf < 12; ++nf) acc[nf] = (f32x4){0.f, 0.f, 0.f, 0.f};

  const float* xp = x + (row0 + r) * (long)D_ + w * 128 + 8 * g;
  const u16* wp = Wt + (long)r * D_ + w * 128 + 8 * g;

  // 4 k-steps of 32; X prefetched one step ahead, W single-buffered (TLP covers)
  float4 xa = *(const float4*)(xp);
  float4 xb = *(const float4*)(xp + 4);
#pragma unroll
  for (int s = 0; s < 4; ++s) {
    float4 na = xa, nb = xb;
    if (s < 3) {
      na = *(const float4*)(xp + 32 * (s + 1));
      nb = *(const float4*)(xp + 32 * (s + 1) + 4);
    }
    bf16x8 a;
    a[0] = (short)f2bf(xa.x); a[1] = (short)f2bf(xa.y);
    a[2] = (short)f2bf(xa.z); a[3] = (short)f2bf(xa.w);
    a[4] = (short)f2bf(xb.x); a[5] = (short)f2bf(xb.y);
    a[6] = (short)f2bf(xb.z); a[7] = (short)f2bf(xb.w);
    const u16* wps = wp + 32 * s;
#pragma unroll
    for (int nf = 0; nf < 12; ++nf) {
      const bf16x8 b = *(const bf16x8*)(wps + (long)nf * 16 * D_);
      acc[nf] = __builtin_amdgcn_mfma_f32_16x16x32_bf16(a, b, acc[nf], 0, 0, 0);
    }
    xa = na; xb = nb;
  }

  // ---- 3-stage tree reduce across 8 waves ----
  if (w >= 4) {
    float* dst = &red[w - 4][lane][0];
#pragma unroll
    for (int nf = 0; nf < 12; ++nf) *(f32x4*)&dst[nf * 4] = acc[nf];
  }
  __syncthreads();
  if (w < 4) {
    const float* src = &red[w][lane][0];
#pragma unroll
    for (int nf = 0; nf < 12; ++nf) acc[nf] += *(const f32x4*)&src[nf * 4];
  }
  __syncthreads();
  if (w == 2 || w == 3) {
    float* dst = &red[w - 2][lane][0];
#pragma unroll
    for (int nf = 0; nf < 12; ++nf) *(f32x4*)&dst[nf * 4] = acc[nf];
  }
  __syncthreads();
  if (w < 2) {
    const float* src = &red[w][lane][0];
#pragma unroll
    for (int nf = 0; nf < 12; ++nf) acc[nf] += *(const f32x4*)&src[nf * 4];
  }
  __syncthreads();
  if (w == 1) {
    float* dst = &red[0][lane][0];
#pragma unroll
    for (int nf = 0; nf < 12; ++nf) *(f32x4*)&dst[nf * 4] = acc[nf];
  }
  __syncthreads();
  if (w != 0) return;
  {
    const float* src = &red[0][lane][0];
#pragma unroll
    for (int nf = 0; nf < 12; ++nf) acc[nf] += *(const f32x4*)&src[nf * 4];
  }

  // ---- epilogue (wave 0 only) ----
  const int bb = (int)(row0 >> 11);
  const int srow = (int)(row0 & 2047);

#pragma unroll
  for (int nf = 0; nf < 4; ++nf) {   // Q: cols 0..63, pre-scaled
    const int col = nf * 16 + r;
#pragma unroll
    for (int i = 0; i < 4; ++i)
      Qb[(row0 + 4 * g + i) * H_ + col] = f2bf(acc[nf][i] * QSCALE);
  }
#pragma unroll
  for (int nf = 4; nf < 8; ++nf) {   // K: cols 64..127
    const int col = (nf - 4) * 16 + r;
#pragma unroll
    for (int i = 0; i < 4; ++i)
      Kb[(row0 + 4 * g + i) * H_ + col] = f2bf(acc[nf][i]);
  }
#pragma unroll
  for (int nf = 8; nf < 12; ++nf) {  // V^T: [b][h][s], 4 consecutive s -> 8B store
    const int col = (nf - 8) * 16 + r;
    u16x4 vp;
#pragma unroll
    for (int i = 0; i < 4; ++i) vp[i] = f2bf(acc[nf][i]);
    *(u16x4*)(Vt + ((long)(bb * H_ + col)) * S_ + srow + 4 * g) = vp;
  }
}

// MFMA causal flash attention, swapped QK^T (S^T = K*Q^T), kv-split-4,
// defer-max. Block = 4 waves = one 16-row q-tile x 4 kv-quarters.
// Grid = 8 x 128 = 1024 blocks -> 4 blocks/CU = 4 waves/SIMD.
__global__ __launch_bounds__(256, 4) void attn4_kernel(const u16* __restrict__ Qb,
                                                       const u16* __restrict__ Kb,
                                                       const u16* __restrict__ Vt,
                                                       float* __restrict__ out) {
  __shared__ u16 plds[4][16 * 72];
  __shared__ float plo[4][16][68];
  __shared__ float pml[4][2][16];

  const int b = blockIdx.x >> 7;
  const int qt = blockIdx.x & 127;
  const int w = threadIdx.x >> 6;
  const int lane = threadIdx.x & 63;
  const int r = lane & 15;
  const int g = lane >> 4;
  const int q0 = qt << 4;
  const int T = (qt >> 2) + 1;          // # of 64-wide kv tiles
  const int start = (w * T) >> 2;
  const int end = ((w + 1) * T) >> 2;

  // Q as B-operand: b[i] = Q[q=r][8g+i] (same bytes as before, new role)
  const u16* Qp = Qb + ((long)(b * S_ + q0 + r)) * H_ + 8 * g;
  const bf16x8 bq0 = *(const bf16x8*)Qp;
  const bf16x8 bq1 = *(const bf16x8*)(Qp + 32);

  const u16* Kbase = Kb + (long)b * S_ * H_ + (long)r * H_ + 8 * g;
  const u16* Vbase = Vt + (long)b * H_ * S_ + (long)r * S_ + 8 * g;

  f32x4 o[4];
#pragma unroll
  for (int nf = 0; nf < 4; ++nf) o[nf] = (f32x4){0.f, 0.f, 0.f, 0.f};
  float m = -INFINITY, l = 0.f;

  u16* pw = plds[w];

  bf16x8 ka[8];  // K as A-operand: a[i] = K[k0+16kf+r][8g+i]
  if (start < end) {
    const int k0 = start << 6;
#pragma unroll
    for (int kf = 0; kf < 4; ++kf) {
      const u16* Kp = Kbase + (long)(k0 + kf * 16) * H_;
      ka[2 * kf] = *(const bf16x8*)(Kp);
      ka[2 * kf + 1] = *(const bf16x8*)(Kp + 32);
    }
  }

  for (int kt = start; kt < end; ++kt) {
    const int k0 = kt << 6;

    // ---- S^T tile: rows k (4g+i within 16kf), col q=r ----
    f32x4 t4[4];
#pragma unroll
    for (int kf = 0; kf < 4; ++kf) {
      f32x4 t = (f32x4){0.f, 0.f, 0.f, 0.f};
      t = __builtin_amdgcn_mfma_f32_16x16x32_bf16(ka[2 * kf], bq0, t, 0, 0, 0);
      t = __builtin_amdgcn_mfma_f32_16x16x32_bf16(ka[2 * kf + 1], bq1, t, 0, 0, 0);
      t4[kf] = t;
    }

    // ---- early V loads (fly under softmax) ----
    bf16x8 vv[8];
#pragma unroll
    for (int nf = 0; nf < 4; ++nf) {
      const u16* Vp = Vbase + (long)(nf * 16) * S_ + k0;
      vv[2 * nf] = *(const bf16x8*)(Vp);
      vv[2 * nf + 1] = *(const bf16x8*)(Vp + 32);
    }
    // ---- prefetch next K tile (overwrites ka; used next iter) ----
    if (kt + 1 < end) {
      const int kn = (kt + 1) << 6;
#pragma unroll
      for (int kf = 0; kf < 4; ++kf) {
        const u16* Kp = Kbase + (long)(kn + kf * 16) * H_;
        ka[2 * kf] = *(const bf16x8*)(Kp);
        ka[2 * kf + 1] = *(const bf16x8*)(Kp + 32);
      }
    }

    if (kt == T - 1) {  // diagonal tile: causal mask (k > q)
#pragma unroll
      for (int kf = 0; kf < 4; ++kf)
#pragma unroll
        for (int i = 0; i < 4; ++i) {
          const int k = k0 + kf * 16 + 4 * g + i;
          if (k > q0 + r) t4[kf][i] = -INFINITY;
        }
    }

    // ---- row max: 15 in-lane + 2 shfl (row q=r replicated over g) ----
    float pm = t4[0][0];
#pragma unroll
    for (int kf = 0; kf < 4; ++kf)
#pragma unroll
      for (int i = 0; i < 4; ++i) pm = fmaxf(pm, t4[kf][i]);
    pm = fmaxf(pm, __shfl_xor(pm, 16));
    pm = fmaxf(pm, __shfl_xor(pm, 32));

    // ---- defer-max: rescale only when max grew past threshold ----
    if (__any(pm > m + 8.f)) {
      const float mn = fmaxf(m, pm);
      const float sc = exp2f(m - mn);
      m = mn;
      l *= sc;
      float scr[4];
#pragma unroll
      for (int i = 0; i < 4; ++i) scr[i] = __shfl(sc, 4 * g + i);  // o rows = 4g+i
#pragma unroll
      for (int nf = 0; nf < 4; ++nf)
#pragma unroll
        for (int i = 0; i < 4; ++i) o[nf][i] *= scr[i];
    }

    // ---- P = exp2(S - m), in-lane sum + 2 shfl ----
    float ps = 0.f;
#pragma unroll
    for (int kf = 0; kf < 4; ++kf)
#pragma unroll
      for (int i = 0; i < 4; ++i) {
        const float p = exp2f(t4[kf][i] - m);
        t4[kf][i] = p;
        ps += p;
      }
    ps += __shfl_xor(ps, 16);
    ps += __shfl_xor(ps, 32);
    l += ps;

    // ---- P -> LDS: 4x ds_write_b64 (row q=r, k contiguous) ----
#pragma unroll
    for (int kf = 0; kf < 4; ++kf) {
      u16x4 pk;
#pragma unroll
      for (int i = 0; i < 4; ++i) pk[i] = f2bf(t4[kf][i]);
      *(u16x4*)(pw + r * 72 + kf * 16 + 4 * g) = pk;
    }

    const bf16x8 pa0 = *(const bf16x8*)(pw + r * 72 + 8 * g);
    const bf16x8 pa1 = *(const bf16x8*)(pw + r * 72 + 32 + 8 * g);

    // ---- PV: O[16q x 64h] += P * V ----
#pragma unroll
    for (int nf = 0; nf < 4; ++nf) {
      o[nf] = __builtin_amdgcn_mfma_f32_16x16x32_bf16(pa0, vv[2 * nf], o[nf], 0, 0, 0);
      o[nf] = __builtin_amdgcn_mfma_f32_16x16x32_bf16(pa1, vv[2 * nf + 1], o[nf], 0, 0, 0);
    }
  }

  // ---- write partials ----
#pragma unroll
  for (int nf = 0; nf < 4; ++nf)
#pragma unroll
    for (int i = 0; i < 4; ++i)
      plo[w][4 * g + i][nf * 16 + r] = o[nf][i];
  if (g == 0) {
    pml[w][0][r] = m;
    pml[w][1][r] = l;
  }
  __syncthreads();

  // ---- 4-way merge; thread -> (row, 4 cols) ----
  const int row = (w << 2) + g;
  const int c0 = (lane & 15) << 2;
  const float m0 = pml[0][0][row], m1 = pml[1][0][row];
  const float m2 = pml[2][0][row], m3 = pml[3][0][row];
  const float M = fmaxf(fmaxf(m0, m1), fmaxf(m2, m3));
  const float e0 = exp2f(m0 - M), e1 = exp2f(m1 - M);
  const float e2 = exp2f(m2 - M), e3 = exp2f(m3 - M);
  const float L = pml[0][1][row] * e0 + pml[1][1][row] * e1 +
                  pml[2][1][row] * e2 + pml[3][1][row] * e3;
  const float inv = 1.f / L;
  f32x4 os;
#pragma unroll
  for (int c = 0; c < 4; ++c)
    os[c] = (plo[0][row][c0 + c] * e0 + plo[1][row][c0 + c] * e1 +
             plo[2][row][c0 + c] * e2 + plo[3][row][c0 + c] * e3) * inv;
  *(f32x4*)(out + ((long)(b * S_ + q0 + row)) * H_ + c0) = os;
}

extern "C" void kernel_launch(void* const* d_in, const int* in_sizes, int n_in,
                              void* d_out, int out_size, void* d_ws, size_t ws_size,
                              hipStream_t stream) {
  const float* x  = (const float*)d_in[0];
  const float* Wk = (const float*)d_in[1];
  const float* Wq = (const float*)d_in[2];
  const float* Wv = (const float*)d_in[3];
  float* out = (float*)d_out;

  u16* Qb = (u16*)d_ws;                                   // 2 MiB
  u16* Kb = Qb + (long)B_ * S_ * H_;                      // 2 MiB
  u16* Vt = Kb + (long)B_ * S_ * H_;                      // 2 MiB
  u16* Wt = Vt + (long)B_ * S_ * H_;                      // 384 KiB

  wprep_kernel<<<192, 256, 0, stream>>>(Wk, Wq, Wv, Wt);
  qkv_kernel<<<1024, 512, 0, stream>>>(x, Wt, Qb, Kb, Vt);
  attn4_kernel<<<B_ * 128, 256, 0, stream>>>(Qb, Kb, Vt, out);
}

// Round 7
// 103.760 us; speedup vs baseline: 1.2250x; 1.2250x over previous
//
#include <hip/hip_runtime.h>
#include <hip/hip_bf16.h>

#define B_ 8
#define S_ 2048
#define D_ 1024
#define H_ 64

typedef __attribute__((ext_vector_type(8))) short bf16x8;
typedef __attribute__((ext_vector_type(4))) float f32x4;
typedef __attribute__((ext_vector_type(4))) unsigned short u16x4;
typedef unsigned short u16;
typedef unsigned int u32;

// fold 1/sqrt(64) and log2(e) into Q so softmax can use exp2
#define QSCALE 0.18033688011112042f

static __device__ __forceinline__ u16 f2bf(float f) {
  union { float f; unsigned u; } v; v.f = f;
  unsigned r = v.u + 0x7FFFu + ((v.u >> 16) & 1u);
  return (u16)(r >> 16);
}

// Build Wt [192][1024] bf16: rows 0..63 = Wq cols, 64..127 = Wk, 128..191 = Wv.
__global__ __launch_bounds__(256) void wprep_kernel(const float* __restrict__ Wk,
                                                    const float* __restrict__ Wq,
                                                    const float* __restrict__ Wv,
                                                    u16* __restrict__ Wt) {
  const int c = blockIdx.x;  // 0..191
  const float* W = (c < 64) ? Wq : ((c < 128) ? Wk : Wv);
  const int cc = c & 63;
  for (int d = threadIdx.x; d < D_; d += blockDim.x)
    Wt[c * D_ + d] = f2bf(W[d * H_ + cc]);
}

// QKV projection v5: W-stationary registers + X streamed via global_load_lds.
// Block = 1024 threads = 16 waves = 4 col-groups (48 cols) x 4 k-slices (256 k).
// Each block processes 4 chunks of 16 rows (grid-stride), X chunk (64 KB fp32)
// double-buffered in LDS with XOR-swizzled layout; per-chunk LDS tree-reduce
// over k-slices; ks==0 waves write the Q/K/V epilogue.
__global__ __launch_bounds__(1024) void qkv_kernel(const float* __restrict__ x,
                                                   const u16* __restrict__ Wt,
                                                   u16* __restrict__ Qb,
                                                   u16* __restrict__ Kb,
                                                   u16* __restrict__ Vt) {
  __shared__ float xbuf[2][16384];   // 2 x 64 KB
  __shared__ float red[8][64][12];   // 24 KB

  const int tid = threadIdx.x;
  const int w = tid >> 6;
  const int lane = tid & 63;
  const int r = lane & 15;
  const int g = lane >> 4;
  const int cg = w & 3;    // col-group: cols 48*cg .. 48*cg+47
  const int ks = w >> 2;   // k-slice:  k 256*ks .. 256*ks+255

  const u16* wbase = Wt + (size_t)(cg * 48 + r) * D_ + ks * 256 + g * 8;
  const int rswz = (r & 7) << 4;

  f32x4 acc[3];
  acc[0] = acc[1] = acc[2] = (f32x4){0.f, 0.f, 0.f, 0.f};

  // Stage one 16-row chunk (64 KB, contiguous in x) into xbuf[buf] with the
  // involutive swizzle L -> L ^ ((row&7)<<4) applied on the GLOBAL source.
#define STAGE(chunk, buf)                                                     \
  {                                                                           \
    const char* gbase = (const char*)x + (size_t)(chunk) * 65536;             \
    _Pragma("unroll") for (int j = 0; j < 4; ++j) {                           \
      const int L = j * 16384 + tid * 16;                                     \
      const int Ls = L ^ (((L >> 12) & 7) << 4);                              \
      __builtin_amdgcn_global_load_lds(                                       \
          (const __attribute__((address_space(1))) u32*)(gbase + Ls),         \
          (__attribute__((address_space(3))) u32*)((char*)&xbuf[buf][0] +     \
                                                   j * 16384 + w * 1024),     \
          16, 0, 0);                                                          \
    }                                                                         \
  }

  STAGE(blockIdx.x, 0);
  int cur = 0;

  for (int i = 0; i < 4; ++i) {
    const long row0 = ((long)blockIdx.x + (long)i * 256) * 16;
    __syncthreads();  // xbuf[cur] ready (compiler drains vmcnt before barrier)
    if (i < 3) STAGE(blockIdx.x + (i + 1) * 256, cur ^ 1);

    const char* xb = (const char*)&xbuf[cur][0];
#pragma unroll
    for (int h = 0; h < 2; ++h) {
      // W fragments for this 128-k half (48 VGPR), reloaded from hot L2
      bf16x8 wf0[4], wf1[4], wf2[4];
#pragma unroll
      for (int s = 0; s < 4; ++s) {
        wf0[s] = *(const bf16x8*)(wbase + 0 * 16 * D_ + h * 128 + s * 32);
        wf1[s] = *(const bf16x8*)(wbase + 1 * 16 * D_ + h * 128 + s * 32);
        wf2[s] = *(const bf16x8*)(wbase + 2 * 16 * D_ + h * 128 + s * 32);
      }
#pragma unroll
      for (int s = 0; s < 4; ++s) {
        const int alin = r * 4096 + (ks * 256 + h * 128 + s * 32 + g * 8) * 4;
        const float4 lo = *(const float4*)(xb + (alin ^ rswz));
        const float4 hi = *(const float4*)(xb + ((alin + 16) ^ rswz));
        bf16x8 a;
        a[0] = (short)f2bf(lo.x); a[1] = (short)f2bf(lo.y);
        a[2] = (short)f2bf(lo.z); a[3] = (short)f2bf(lo.w);
        a[4] = (short)f2bf(hi.x); a[5] = (short)f2bf(hi.y);
        a[6] = (short)f2bf(hi.z); a[7] = (short)f2bf(hi.w);
        acc[0] = __builtin_amdgcn_mfma_f32_16x16x32_bf16(a, wf0[s], acc[0], 0, 0, 0);
        acc[1] = __builtin_amdgcn_mfma_f32_16x16x32_bf16(a, wf1[s], acc[1], 0, 0, 0);
        acc[2] = __builtin_amdgcn_mfma_f32_16x16x32_bf16(a, wf2[s], acc[2], 0, 0, 0);
      }
    }

    // ---- reduce over k-slices: {1,3} -> LDS; {0,2} add; 2 -> LDS; 0 adds ----
    if (ks & 1) {
      float* dst = &red[(ks >> 1) * 4 + cg][lane][0];
      *(f32x4*)&dst[0] = acc[0]; *(f32x4*)&dst[4] = acc[1]; *(f32x4*)&dst[8] = acc[2];
    }
    __syncthreads();
    if (!(ks & 1)) {
      const float* src = &red[(ks >> 1) * 4 + cg][lane][0];
      acc[0] += *(const f32x4*)&src[0];
      acc[1] += *(const f32x4*)&src[4];
      acc[2] += *(const f32x4*)&src[8];
    }
    __syncthreads();
    if (ks == 2) {
      float* dst = &red[cg][lane][0];
      *(f32x4*)&dst[0] = acc[0]; *(f32x4*)&dst[4] = acc[1]; *(f32x4*)&dst[8] = acc[2];
    }
    __syncthreads();
    if (ks == 0) {
      const float* src = &red[cg][lane][0];
      acc[0] += *(const f32x4*)&src[0];
      acc[1] += *(const f32x4*)&src[4];
      acc[2] += *(const f32x4*)&src[8];

      const int bb = (int)(row0 >> 11);
      const int srow = (int)(row0 & 2047);
#pragma unroll
      for (int nf = 0; nf < 3; ++nf) {
        const int col = cg * 48 + nf * 16 + r;  // frag is wholly in Q, K, or V
        if (col < 64) {
#pragma unroll
          for (int ii = 0; ii < 4; ++ii)
            Qb[(row0 + 4 * g + ii) * H_ + col] = f2bf(acc[nf][ii] * QSCALE);
        } else if (col < 128) {
#pragma unroll
          for (int ii = 0; ii < 4; ++ii)
            Kb[(row0 + 4 * g + ii) * H_ + (col - 64)] = f2bf(acc[nf][ii]);
        } else {
          u16x4 vp;
#pragma unroll
          for (int ii = 0; ii < 4; ++ii) vp[ii] = f2bf(acc[nf][ii]);
          *(u16x4*)(Vt + ((size_t)(bb * H_ + (col - 128))) * S_ + srow + 4 * g) = vp;
        }
      }
    }
    acc[0] = acc[1] = acc[2] = (f32x4){0.f, 0.f, 0.f, 0.f};
    cur ^= 1;
  }
#undef STAGE
}

// MFMA causal flash attention, swapped QK^T (S^T = K*Q^T), kv-split-4,
// defer-max. Block = 4 waves = one 16-row q-tile x 4 kv-quarters.
// Grid = 8 x 128 = 1024 blocks. (256,2): no VGPR cap at 128 -> no spill.
__global__ __launch_bounds__(256, 2) void attn4_kernel(const u16* __restrict__ Qb,
                                                       const u16* __restrict__ Kb,
                                                       const u16* __restrict__ Vt,
                                                       float* __restrict__ out) {
  __shared__ u16 plds[4][16 * 72];
  __shared__ float plo[4][16][68];
  __shared__ float pml[4][2][16];

  const int b = blockIdx.x >> 7;
  const int qt = blockIdx.x & 127;
  const int w = threadIdx.x >> 6;
  const int lane = threadIdx.x & 63;
  const int r = lane & 15;
  const int g = lane >> 4;
  const int q0 = qt << 4;
  const int T = (qt >> 2) + 1;          // # of 64-wide kv tiles
  const int start = (w * T) >> 2;
  const int end = ((w + 1) * T) >> 2;

  // Q as B-operand: b[i] = Q[q=r][8g+i]
  const u16* Qp = Qb + ((long)(b * S_ + q0 + r)) * H_ + 8 * g;
  const bf16x8 bq0 = *(const bf16x8*)Qp;
  const bf16x8 bq1 = *(const bf16x8*)(Qp + 32);

  const u16* Kbase = Kb + (long)b * S_ * H_ + (long)r * H_ + 8 * g;
  const u16* Vbase = Vt + (long)b * H_ * S_ + (long)r * S_ + 8 * g;

  f32x4 o[4];
#pragma unroll
  for (int nf = 0; nf < 4; ++nf) o[nf] = (f32x4){0.f, 0.f, 0.f, 0.f};
  float m = -INFINITY, l = 0.f;

  u16* pw = plds[w];

  bf16x8 ka[8];  // K as A-operand: a[i] = K[k0+16kf+r][8g+i]
  if (start < end) {
    const int k0 = start << 6;
#pragma unroll
    for (int kf = 0; kf < 4; ++kf) {
      const u16* Kp = Kbase + (long)(k0 + kf * 16) * H_;
      ka[2 * kf] = *(const bf16x8*)(Kp);
      ka[2 * kf + 1] = *(const bf16x8*)(Kp + 32);
    }
  }

  for (int kt = start; kt < end; ++kt) {
    const int k0 = kt << 6;

    // ---- S^T tile: rows k (4g+i within 16kf), col q=r ----
    f32x4 t4[4];
#pragma unroll
    for (int kf = 0; kf < 4; ++kf) {
      f32x4 t = (f32x4){0.f, 0.f, 0.f, 0.f};
      t = __builtin_amdgcn_mfma_f32_16x16x32_bf16(ka[2 * kf], bq0, t, 0, 0, 0);
      t = __builtin_amdgcn_mfma_f32_16x16x32_bf16(ka[2 * kf + 1], bq1, t, 0, 0, 0);
      t4[kf] = t;
    }

    // ---- early V loads (fly under softmax) ----
    bf16x8 vv[8];
#pragma unroll
    for (int nf = 0; nf < 4; ++nf) {
      const u16* Vp = Vbase + (long)(nf * 16) * S_ + k0;
      vv[2 * nf] = *(const bf16x8*)(Vp);
      vv[2 * nf + 1] = *(const bf16x8*)(Vp + 32);
    }
    // ---- prefetch next K tile ----
    if (kt + 1 < end) {
      const int kn = (kt + 1) << 6;
#pragma unroll
      for (int kf = 0; kf < 4; ++kf) {
        const u16* Kp = Kbase + (long)(kn + kf * 16) * H_;
        ka[2 * kf] = *(const bf16x8*)(Kp);
        ka[2 * kf + 1] = *(const bf16x8*)(Kp + 32);
      }
    }

    if (kt == T - 1) {  // diagonal tile: causal mask (k > q)
#pragma unroll
      for (int kf = 0; kf < 4; ++kf)
#pragma unroll
        for (int i = 0; i < 4; ++i) {
          const int k = k0 + kf * 16 + 4 * g + i;
          if (k > q0 + r) t4[kf][i] = -INFINITY;
        }
    }

    // ---- row max: 15 in-lane + 2 shfl ----
    float pm = t4[0][0];
#pragma unroll
    for (int kf = 0; kf < 4; ++kf)
#pragma unroll
      for (int i = 0; i < 4; ++i) pm = fmaxf(pm, t4[kf][i]);
    pm = fmaxf(pm, __shfl_xor(pm, 16));
    pm = fmaxf(pm, __shfl_xor(pm, 32));

    // ---- defer-max: rescale only when max grew past threshold ----
    if (__any(pm > m + 8.f)) {
      const float mn = fmaxf(m, pm);
      const float sc = exp2f(m - mn);
      m = mn;
      l *= sc;
      float scr[4];
#pragma unroll
      for (int i = 0; i < 4; ++i) scr[i] = __shfl(sc, 4 * g + i);
#pragma unroll
      for (int nf = 0; nf < 4; ++nf)
#pragma unroll
        for (int i = 0; i < 4; ++i) o[nf][i] *= scr[i];
    }

    // ---- P = exp2(S - m), in-lane sum + 2 shfl ----
    float ps = 0.f;
#pragma unroll
    for (int kf = 0; kf < 4; ++kf)
#pragma unroll
      for (int i = 0; i < 4; ++i) {
        const float p = exp2f(t4[kf][i] - m);
        t4[kf][i] = p;
        ps += p;
      }
    ps += __shfl_xor(ps, 16);
    ps += __shfl_xor(ps, 32);
    l += ps;

    // ---- P -> LDS: 4x ds_write_b64 ----
#pragma unroll
    for (int kf = 0; kf < 4; ++kf) {
      u16x4 pk;
#pragma unroll
      for (int i = 0; i < 4; ++i) pk[i] = f2bf(t4[kf][i]);
      *(u16x4*)(pw + r * 72 + kf * 16 + 4 * g) = pk;
    }

    const bf16x8 pa0 = *(const bf16x8*)(pw + r * 72 + 8 * g);
    const bf16x8 pa1 = *(const bf16x8*)(pw + r * 72 + 32 + 8 * g);

    // ---- PV ----
#pragma unroll
    for (int nf = 0; nf < 4; ++nf) {
      o[nf] = __builtin_amdgcn_mfma_f32_16x16x32_bf16(pa0, vv[2 * nf], o[nf], 0, 0, 0);
      o[nf] = __builtin_amdgcn_mfma_f32_16x16x32_bf16(pa1, vv[2 * nf + 1], o[nf], 0, 0, 0);
    }
  }

  // ---- write partials ----
#pragma unroll
  for (int nf = 0; nf < 4; ++nf)
#pragma unroll
    for (int i = 0; i < 4; ++i)
      plo[w][4 * g + i][nf * 16 + r] = o[nf][i];
  if (g == 0) {
    pml[w][0][r] = m;
    pml[w][1][r] = l;
  }
  __syncthreads();

  // ---- 4-way merge; thread -> (row, 4 cols) ----
  const int row = (w << 2) + g;
  const int c0 = (lane & 15) << 2;
  const float m0 = pml[0][0][row], m1 = pml[1][0][row];
  const float m2 = pml[2][0][row], m3 = pml[3][0][row];
  const float M = fmaxf(fmaxf(m0, m1), fmaxf(m2, m3));
  const float e0 = exp2f(m0 - M), e1 = exp2f(m1 - M);
  const float e2 = exp2f(m2 - M), e3 = exp2f(m3 - M);
  const float L = pml[0][1][row] * e0 + pml[1][1][row] * e1 +
                  pml[2][1][row] * e2 + pml[3][1][row] * e3;
  const float inv = 1.f / L;
  f32x4 os;
#pragma unroll
  for (int c = 0; c < 4; ++c)
    os[c] = (plo[0][row][c0 + c] * e0 + plo[1][row][c0 + c] * e1 +
             plo[2][row][c0 + c] * e2 + plo[3][row][c0 + c] * e3) * inv;
  *(f32x4*)(out + ((long)(b * S_ + q0 + row)) * H_ + c0) = os;
}

extern "C" void kernel_launch(void* const* d_in, const int* in_sizes, int n_in,
                              void* d_out, int out_size, void* d_ws, size_t ws_size,
                              hipStream_t stream) {
  const float* x  = (const float*)d_in[0];
  const float* Wk = (const float*)d_in[1];
  const float* Wq = (const float*)d_in[2];
  const float* Wv = (const float*)d_in[3];
  float* out = (float*)d_out;

  u16* Qb = (u16*)d_ws;                                   // 2 MiB
  u16* Kb = Qb + (long)B_ * S_ * H_;                      // 2 MiB
  u16* Vt = Kb + (long)B_ * S_ * H_;                      // 2 MiB
  u16* Wt = Vt + (long)B_ * S_ * H_;                      // 384 KiB

  wprep_kernel<<<192, 256, 0, stream>>>(Wk, Wq, Wv, Wt);
  qkv_kernel<<<256, 1024, 0, stream>>>(x, Wt, Qb, Kb, Vt);
  attn4_kernel<<<B_ * 128, 256, 0, stream>>>(Qb, Kb, Vt, out);
}

// Round 8
// 96.063 us; speedup vs baseline: 1.3232x; 1.0801x over previous
//
#include <hip/hip_runtime.h>
#include <hip/hip_bf16.h>

#define B_ 8
#define S_ 2048
#define D_ 1024
#define H_ 64

typedef __attribute__((ext_vector_type(8))) short bf16x8;
typedef __attribute__((ext_vector_type(4))) float f32x4;
typedef __attribute__((ext_vector_type(4))) unsigned short u16x4;
typedef unsigned short u16;

// fold 1/sqrt(64) and log2(e) into Q so softmax can use exp2
#define QSCALE 0.18033688011112042f

static __device__ __forceinline__ u16 f2bf(float f) {
  union { float f; unsigned u; } v; v.f = f;
  unsigned r = v.u + 0x7FFFu + ((v.u >> 16) & 1u);
  return (u16)(r >> 16);
}

// Build Wt [192][1024] bf16: rows 0..63 = Wq cols, 64..127 = Wk, 128..191 = Wv.
__global__ __launch_bounds__(256) void wprep_kernel(const float* __restrict__ Wk,
                                                    const float* __restrict__ Wq,
                                                    const float* __restrict__ Wv,
                                                    u16* __restrict__ Wt) {
  const int c = blockIdx.x;  // 0..191
  const float* W = (c < 64) ? Wq : ((c < 128) ? Wk : Wv);
  const int cc = c & 63;
  for (int d = threadIdx.x; d < D_; d += blockDim.x)
    Wt[c * D_ + d] = f2bf(W[d * H_ + cc]);
}

// QKV projection v6: W-stationary registers, x streamed direct from global.
// Block = 256 threads = 4 waves = 4 K-slices (256 k each) of ONE col-group
// (48 cols). Each wave holds its 24 W-fragments (96 VGPR) across the whole
// block. Block processes 4 chunks of 16 rows; per-chunk all-write LDS
// reduce with rotating merge wave (1 barrier/chunk, double-buffered).
// Grid = 256 row-groups x 4 col-groups = 1024 blocks.
__global__ __launch_bounds__(256) void qkv_kernel(const float* __restrict__ x,
                                                  const u16* __restrict__ Wt,
                                                  u16* __restrict__ Qb,
                                                  u16* __restrict__ Kb,
                                                  u16* __restrict__ Vt) {
  __shared__ float red[2][4][64][12];  // 24.5 KB

  const int cgrp = blockIdx.x >> 2;    // row-group: rows cgrp*64 .. +63
  const int cg = blockIdx.x & 3;       // col-group: cols cg*48 .. +47
  const int w = threadIdx.x >> 6;      // k-slice: k in [w*256, w*256+256)
  const int lane = threadIdx.x & 63;
  const int r = lane & 15;
  const int g = lane >> 4;

  // ---- W fragments, loaded ONCE, resident in VGPRs (24 x bf16x8 = 96) ----
  const u16* wbase = Wt + (size_t)(cg * 48 + r) * D_ + w * 256 + g * 8;
  bf16x8 wf[3][8];
#pragma unroll
  for (int nf = 0; nf < 3; ++nf)
#pragma unroll
    for (int s = 0; s < 8; ++s)
      wf[nf][s] = *(const bf16x8*)(wbase + (size_t)nf * 16 * D_ + s * 32);

  const float* xrow = x + ((size_t)cgrp * 64 + r) * D_ + w * 256 + g * 8;

  // x prefetch registers, carried across chunk boundaries
  float4 xa = *(const float4*)(xrow);
  float4 xb = *(const float4*)(xrow + 4);

  for (int c = 0; c < 4; ++c) {
    const float* xp = xrow + (size_t)c * 16 * D_;
    f32x4 a0 = (f32x4){0.f, 0.f, 0.f, 0.f};
    f32x4 a1 = a0, a2 = a0;

#pragma unroll
    for (int s = 0; s < 8; ++s) {
      float4 na = xa, nb = xb;
      if (s < 7) {
        na = *(const float4*)(xp + 32 * (s + 1));
        nb = *(const float4*)(xp + 32 * (s + 1) + 4);
      } else if (c < 3) {
        na = *(const float4*)(xp + 16 * D_);
        nb = *(const float4*)(xp + 16 * D_ + 4);
      }
      bf16x8 a;
      a[0] = (short)f2bf(xa.x); a[1] = (short)f2bf(xa.y);
      a[2] = (short)f2bf(xa.z); a[3] = (short)f2bf(xa.w);
      a[4] = (short)f2bf(xb.x); a[5] = (short)f2bf(xb.y);
      a[6] = (short)f2bf(xb.z); a[7] = (short)f2bf(xb.w);
      a0 = __builtin_amdgcn_mfma_f32_16x16x32_bf16(a, wf[0][s], a0, 0, 0, 0);
      a1 = __builtin_amdgcn_mfma_f32_16x16x32_bf16(a, wf[1][s], a1, 0, 0, 0);
      a2 = __builtin_amdgcn_mfma_f32_16x16x32_bf16(a, wf[2][s], a2, 0, 0, 0);
      xa = na; xb = nb;
    }

    // ---- all waves write partials; rotating wave merges + stores ----
    const int buf = c & 1;
    float* dst = &red[buf][w][lane][0];
    *(f32x4*)&dst[0] = a0;
    *(f32x4*)&dst[4] = a1;
    *(f32x4*)&dst[8] = a2;
    __syncthreads();

    if (w == (c & 3)) {
      f32x4 s0 = (f32x4){0.f, 0.f, 0.f, 0.f}, s1 = s0, s2 = s0;
#pragma unroll
      for (int sw = 0; sw < 4; ++sw) {
        const float* src = &red[buf][sw][lane][0];
        s0 += *(const f32x4*)&src[0];
        s1 += *(const f32x4*)&src[4];
        s2 += *(const f32x4*)&src[8];
      }
      const long row0 = (long)cgrp * 64 + c * 16;
      const int bb = (int)(row0 >> 11);
      const int srow = (int)(row0 & 2047);
      f32x4 sv[3] = {s0, s1, s2};
#pragma unroll
      for (int nf = 0; nf < 3; ++nf) {
        const int col = cg * 48 + nf * 16 + r;  // frag wholly in Q, K, or V
        if (col < 64) {
#pragma unroll
          for (int ii = 0; ii < 4; ++ii)
            Qb[(row0 + 4 * g + ii) * H_ + col] = f2bf(sv[nf][ii] * QSCALE);
        } else if (col < 128) {
#pragma unroll
          for (int ii = 0; ii < 4; ++ii)
            Kb[(row0 + 4 * g + ii) * H_ + (col - 64)] = f2bf(sv[nf][ii]);
        } else {
          u16x4 vp;
#pragma unroll
          for (int ii = 0; ii < 4; ++ii) vp[ii] = f2bf(sv[nf][ii]);
          *(u16x4*)(Vt + ((size_t)(bb * H_ + (col - 128))) * S_ + srow + 4 * g) = vp;
        }
      }
    }
  }
}

// MFMA causal flash attention with 2-way KV split (round-4 attn3, verbatim).
// Block = 4 waves: waves {0,1} = q-tile j (kv halves 0,1), waves {2,3} = q-tile 127-j.
// Grid = 8 batches x 64 pairs = 512 blocks -> 2 blocks/CU.
__global__ __launch_bounds__(256) void attn3_kernel(const u16* __restrict__ Qb,
                                                    const u16* __restrict__ Kb,
                                                    const u16* __restrict__ Vt,
                                                    float* __restrict__ out) {
  __shared__ u16 plds[4][16 * 72];
  __shared__ float plo[4][16][68];
  __shared__ float pml[4][2][16];

  const int b = blockIdx.x >> 6;
  const int j = blockIdx.x & 63;
  const int w = threadIdx.x >> 6;
  const int lane = threadIdx.x & 63;
  const int r = lane & 15;
  const int g = lane >> 4;

  const int qt = (w < 2) ? j : (127 - j);
  const int s = w & 1;
  const int q0 = qt << 4;
  const int T = (qt >> 2) + 1;          // # of 64-wide kv tiles
  const int half = (T + 1) >> 1;
  const int start = s ? half : 0;
  const int end = s ? T : half;

  // Q A-fragments (hoisted)
  const u16* Qp = Qb + ((long)(b * S_ + q0 + r)) * H_ + 8 * g;
  const bf16x8 aq0 = *(const bf16x8*)Qp;
  const bf16x8 aq1 = *(const bf16x8*)(Qp + 32);

  const u16* Kbase = Kb + (long)b * S_ * H_ + (long)r * H_ + 8 * g;
  const u16* Vbase = Vt + (long)b * H_ * S_ + (long)r * S_ + 8 * g;

  f32x4 o[4];
#pragma unroll
  for (int nf = 0; nf < 4; ++nf) o[nf] = (f32x4){0.f, 0.f, 0.f, 0.f};
  float mrow[4] = {-INFINITY, -INFINITY, -INFINITY, -INFINITY};
  float lrow[4] = {0.f, 0.f, 0.f, 0.f};

  u16* pw = plds[w];

  bf16x8 kc[8];
  if (start < end) {
    const int k0 = start << 6;
#pragma unroll
    for (int nf = 0; nf < 4; ++nf) {
      const u16* Kp = Kbase + (long)(k0 + nf * 16) * H_;
      kc[2 * nf] = *(const bf16x8*)(Kp);
      kc[2 * nf + 1] = *(const bf16x8*)(Kp + 32);
    }
  }

  for (int kt = start; kt < end; ++kt) {
    const int k0 = kt << 6;

    // ---- QK^T ----
    f32x4 sf[4];
#pragma unroll
    for (int nf = 0; nf < 4; ++nf) {
      f32x4 t = (f32x4){0.f, 0.f, 0.f, 0.f};
      t = __builtin_amdgcn_mfma_f32_16x16x32_bf16(aq0, kc[2 * nf], t, 0, 0, 0);
      t = __builtin_amdgcn_mfma_f32_16x16x32_bf16(aq1, kc[2 * nf + 1], t, 0, 0, 0);
      sf[nf] = t;
    }

    // ---- early V loads (fly under softmax) ----
    bf16x8 vv[8];
#pragma unroll
    for (int nf = 0; nf < 4; ++nf) {
      const u16* Vp = Vbase + (long)(nf * 16) * S_ + k0;
      vv[2 * nf] = *(const bf16x8*)(Vp);
      vv[2 * nf + 1] = *(const bf16x8*)(Vp + 32);
    }
    // ---- prefetch next K tile ----
    if (kt + 1 < end) {
      const int kn = (kt + 1) << 6;
#pragma unroll
      for (int nf = 0; nf < 4; ++nf) {
        const u16* Kp = Kbase + (long)(kn + nf * 16) * H_;
        kc[2 * nf] = *(const bf16x8*)(Kp);
        kc[2 * nf + 1] = *(const bf16x8*)(Kp + 32);
      }
    }

    if (kt == T - 1) {  // diagonal tile: causal mask
#pragma unroll
      for (int nf = 0; nf < 4; ++nf)
#pragma unroll
        for (int i = 0; i < 4; ++i) {
          const int k = k0 + nf * 16 + r;
          const int q = q0 + 4 * g + i;
          if (k > q) sf[nf][i] = -INFINITY;
        }
    }

    // ---- online softmax (rows in 16-lane groups) ----
    float fm[4];
#pragma unroll
    for (int i = 0; i < 4; ++i)
      fm[i] = fmaxf(fmaxf(sf[0][i], sf[1][i]), fmaxf(sf[2][i], sf[3][i]));
#pragma unroll
    for (int off = 8; off >= 1; off >>= 1)
#pragma unroll
      for (int i = 0; i < 4; ++i)
        fm[i] = fmaxf(fm[i], __shfl_xor(fm[i], off));

    float sc[4];
#pragma unroll
    for (int i = 0; i < 4; ++i) {
      const float mn = fmaxf(mrow[i], fm[i]);
      sc[i] = exp2f(mrow[i] - mn);
      mrow[i] = mn;
    }

    float ps[4] = {0.f, 0.f, 0.f, 0.f};
#pragma unroll
    for (int nf = 0; nf < 4; ++nf)
#pragma unroll
      for (int i = 0; i < 4; ++i) {
        const float p = exp2f(sf[nf][i] - mrow[i]);
        sf[nf][i] = p;
        ps[i] += p;
      }
#pragma unroll
    for (int off = 8; off >= 1; off >>= 1)
#pragma unroll
      for (int i = 0; i < 4; ++i)
        ps[i] += __shfl_xor(ps[i], off);

#pragma unroll
    for (int i = 0; i < 4; ++i) lrow[i] = lrow[i] * sc[i] + ps[i];
#pragma unroll
    for (int nf = 0; nf < 4; ++nf)
#pragma unroll
      for (int i = 0; i < 4; ++i) o[nf][i] *= sc[i];

    // ---- P -> LDS (bf16), re-fragment as PV A-operand ----
#pragma unroll
    for (int nf = 0; nf < 4; ++nf)
#pragma unroll
      for (int i = 0; i < 4; ++i)
        pw[(4 * g + i) * 72 + nf * 16 + r] = f2bf(sf[nf][i]);

    const bf16x8 pa0 = *(const bf16x8*)(pw + r * 72 + 8 * g);
    const bf16x8 pa1 = *(const bf16x8*)(pw + r * 72 + 32 + 8 * g);

    // ---- PV ----
#pragma unroll
    for (int nf = 0; nf < 4; ++nf) {
      o[nf] = __builtin_amdgcn_mfma_f32_16x16x32_bf16(pa0, vv[2 * nf], o[nf], 0, 0, 0);
      o[nf] = __builtin_amdgcn_mfma_f32_16x16x32_bf16(pa1, vv[2 * nf + 1], o[nf], 0, 0, 0);
    }
  }

  // ---- write partials to LDS ----
#pragma unroll
  for (int nf = 0; nf < 4; ++nf)
#pragma unroll
    for (int i = 0; i < 4; ++i)
      plo[w][4 * g + i][nf * 16 + r] = o[nf][i];
  if (r == 0) {
#pragma unroll
    for (int i = 0; i < 4; ++i) {
      pml[w][0][4 * g + i] = mrow[i];
      pml[w][1][4 * g + i] = lrow[i];
    }
  }
  __syncthreads();

  // ---- merge the two kv-halves; each wave writes 8 rows of one q-tile ----
  const int base = (w >> 1) << 1;
  const int hlf = w & 1;
  const int qq0 = ((base == 0) ? j : (127 - j)) << 4;
#pragma unroll
  for (int rr = 0; rr < 8; ++rr) {
    const int row = hlf * 8 + rr;
    const float mA = pml[base][0][row], mB = pml[base + 1][0][row];
    const float lA = pml[base][1][row], lB = pml[base + 1][1][row];
    const float M = fmaxf(mA, mB);
    const float ea = exp2f(mA - M), eb = exp2f(mB - M);
    const float inv = 1.f / (lA * ea + lB * eb);
    const float oo = plo[base][row][lane] * ea + plo[base + 1][row][lane] * eb;
    out[((long)(b * S_ + qq0 + row)) * H_ + lane] = oo * inv;
  }
}

extern "C" void kernel_launch(void* const* d_in, const int* in_sizes, int n_in,
                              void* d_out, int out_size, void* d_ws, size_t ws_size,
                              hipStream_t stream) {
  const float* x  = (const float*)d_in[0];
  const float* Wk = (const float*)d_in[1];
  const float* Wq = (const float*)d_in[2];
  const float* Wv = (const float*)d_in[3];
  float* out = (float*)d_out;

  u16* Qb = (u16*)d_ws;                                   // 2 MiB
  u16* Kb = Qb + (long)B_ * S_ * H_;                      // 2 MiB
  u16* Vt = Kb + (long)B_ * S_ * H_;                      // 2 MiB
  u16* Wt = Vt + (long)B_ * S_ * H_;                      // 384 KiB

  wprep_kernel<<<192, 256, 0, stream>>>(Wk, Wq, Wv, Wt);
  qkv_kernel<<<1024, 256, 0, stream>>>(x, Wt, Qb, Kb, Vt);
  attn3_kernel<<<B_ * 64, 256, 0, stream>>>(Qb, Kb, Vt, out);
}